// Round 5
// baseline (192.099 us; speedup 1.0000x reference)
//
#include <hip/hip_runtime.h>

// B=4, C=C2=1024, E=1024, D=1024, NH(head dim)=16, G=64 groups. Rows B*C=4096.

typedef _Float16 f16x8 __attribute__((ext_vector_type(8)));
typedef _Float16 f16x4 __attribute__((ext_vector_type(4)));
typedef _Float16 f16x2 __attribute__((ext_vector_type(2)));
typedef float    f32x4 __attribute__((ext_vector_type(4)));
typedef float    f32x16 __attribute__((ext_vector_type(16)));

// global -> LDS direct DMA, 16 B per lane. LDS dest = wave-uniform base + lane*16.
#define GLOAD_LDS16(gp, lp)                                              \
    __builtin_amdgcn_global_load_lds(                                    \
        (const __attribute__((address_space(1))) void*)(gp),             \
        (__attribute__((address_space(3))) void*)(lp), 16, 0, 0)

static __device__ __forceinline__ f16x8 pack8f(const float* p) {
    f16x2 a = __builtin_bit_cast(f16x2, __builtin_amdgcn_cvt_pkrtz(p[0], p[1]));
    f16x2 b = __builtin_bit_cast(f16x2, __builtin_amdgcn_cvt_pkrtz(p[2], p[3]));
    f16x2 c = __builtin_bit_cast(f16x2, __builtin_amdgcn_cvt_pkrtz(p[4], p[5]));
    f16x2 d = __builtin_bit_cast(f16x2, __builtin_amdgcn_cvt_pkrtz(p[6], p[7]));
    f16x8 r;
    r[0] = a[0]; r[1] = a[1]; r[2] = b[0]; r[3] = b[1];
    r[4] = c[0]; r[5] = c[1]; r[6] = d[0]; r[7] = d[1];
    return r;
}

// ---- prep: fp32->fp16 convert of x1,x2 (blocks 0..8191) + transpose-convert of the
// ---- 4 weights into (N,K) f16 (blocks 8192..12287), one launch ----
__global__ __launch_bounds__(256) void prep_kernel(
        const float* __restrict__ x1, const float* __restrict__ x2,
        const float* __restrict__ W0, const float* __restrict__ W1,
        const float* __restrict__ W2, const float* __restrict__ W3,
        _Float16* __restrict__ y1, _Float16* __restrict__ y2,
        _Float16* __restrict__ T0, _Float16* __restrict__ T1,
        _Float16* __restrict__ T2, _Float16* __restrict__ T3) {
    int bx = blockIdx.x, tid = threadIdx.x;
    if (bx < 8192) {
        int i = bx * 256 + tid;              // 2M float4 total
        const float* x = (i < 1048576) ? x1 : x2;
        _Float16* y = (i < 1048576) ? y1 : y2;
        int j = i & 1048575;
        float4 v = ((const float4*)x)[j];
        f16x4 h = { (_Float16)v.x, (_Float16)v.y, (_Float16)v.z, (_Float16)v.w };
        ((f16x4*)y)[j] = h;
    } else {
        int z = (bx - 8192) >> 10;
        const float* W = (z == 0) ? W0 : (z == 1) ? W1 : (z == 2) ? W2 : W3;
        _Float16* WT = (z == 0) ? T0 : (z == 1) ? T1 : (z == 2) ? T2 : T3;
        int t = (bx - 8192) & 1023;
        int c0 = (t & 31) * 32, r0 = (t >> 5) * 32;
        __shared__ float tile[32][33];
        int tx = tid & 31, ty = tid >> 5;    // 32 x 8
#pragma unroll
        for (int i = 0; i < 32; i += 8)
            tile[ty + i][tx] = W[(r0 + ty + i) * 1024 + (c0 + tx)];
        __syncthreads();
#pragma unroll
        for (int i = 0; i < 32; i += 8)
            WT[(c0 + ty + i) * 1024 + (r0 + tx)] = (_Float16)tile[tx][ty + i];
    }
}

// ------------- m97-style MTx128 GEMM body (pre-offset pointers, K=1024) -------------
// block 256 (4 waves, 2x2 over MT x 128), BK=64, global_load_lds w16, 16x16x32 MFMA.
template <int MT, bool OUTF32>
static __device__ __forceinline__ void gemm_body(const _Float16* __restrict__ Atile,
                                                 const _Float16* __restrict__ BTtile,
                                                 void* __restrict__ Ctile,
                                                 _Float16* As, _Float16* Bs) {
    constexpr int AF = MT / 32;              // A staging rounds & m-frags per wave
    const int tid = threadIdx.x, lane = tid & 63, wave = tid >> 6;
    const int wm = wave >> 1, wn = wave & 1;
    const int col = lane & 15, quad = lane >> 4;

    f32x4 acc[AF][4];
#pragma unroll
    for (int i = 0; i < AF; i++)
#pragma unroll
        for (int j = 0; j < 4; j++) acc[i][j] = (f32x4){0.f, 0.f, 0.f, 0.f};

    const int srow = wave * 8 + (lane >> 3);
    const int sch = (lane & 7) * 8;
    const _Float16* Ag = Atile + (size_t)srow * 1024 + sch;
    const _Float16* Bg = BTtile + (size_t)srow * 1024 + sch;
    _Float16* Asl = As + wave * 512;
    _Float16* Bsl = Bs + wave * 512;

    for (int kt = 0; kt < 16; kt++) {
        __syncthreads();
#pragma unroll
        for (int c = 0; c < AF; c++)
            GLOAD_LDS16(Ag + (size_t)(c * 32) * 1024 + kt * 64, Asl + c * 2048);
#pragma unroll
        for (int c = 0; c < 4; c++)
            GLOAD_LDS16(Bg + (size_t)(c * 32) * 1024 + kt * 64, Bsl + c * 2048);
        __syncthreads();
#pragma unroll
        for (int ki = 0; ki < 2; ki++) {
            f16x8 af[AF], bf[4];
#pragma unroll
            for (int i = 0; i < AF; i++)
                af[i] = *(const f16x8*)(As + (wm * (MT / 2) + i * 16 + col) * 64 + ki * 32 + quad * 8);
#pragma unroll
            for (int j = 0; j < 4; j++)
                bf[j] = *(const f16x8*)(Bs + (wn * 64 + j * 16 + col) * 64 + ki * 32 + quad * 8);
#pragma unroll
            for (int i = 0; i < AF; i++)
#pragma unroll
                for (int j = 0; j < 4; j++)
                    acc[i][j] = __builtin_amdgcn_mfma_f32_16x16x32_f16(af[i], bf[j], acc[i][j], 0, 0, 0);
        }
    }

#pragma unroll
    for (int i = 0; i < AF; i++)
#pragma unroll
        for (int ii = 0; ii < 4; ii++) {
            int row = wm * (MT / 2) + i * 16 + quad * 4 + ii;
#pragma unroll
            for (int j = 0; j < 4; j++) {
                int cc = wn * 64 + j * 16 + col;
                if (OUTF32) ((float*)Ctile)[(size_t)row * 1024 + cc] = acc[i][j][ii];
                else ((_Float16*)Ctile)[(size_t)row * 1024 + cc] = (_Float16)acc[i][j][ii];
            }
        }
}

// Fused Q + (KV as N=2048) projections, flat 768-block grid (128x128 tiles):
__global__ __launch_bounds__(256, 3) void gemm_qkv_kernel(
        const _Float16* __restrict__ x1h, const _Float16* __restrict__ x2h,
        const _Float16* __restrict__ WqT, const _Float16* __restrict__ WkvT,
        _Float16* __restrict__ Qh, _Float16* __restrict__ Kh, _Float16* __restrict__ Vh) {
    __shared__ _Float16 As[128 * 64], Bs[128 * 64];
    int gx = blockIdx.x;
    const _Float16 *A, *BT;
    _Float16* C;
    int m0, n0;
    if (gx < 256) {
        m0 = (gx >> 3) * 128; n0 = (gx & 7) * 128;
        A = x1h; BT = WqT + (size_t)n0 * 1024; C = Qh + n0;
    } else {
        int idx = gx - 256;
        m0 = (idx >> 4) * 128;
        int nb = idx & 15;
        n0 = nb * 128;                        // 0..2047 within stacked KV
        A = x2h; BT = WkvT + (size_t)n0 * 1024;
        C = (nb < 8) ? (Kh + n0) : (Vh + (n0 - 1024));
    }
    gemm_body<128, false>(A + (size_t)m0 * 1024, BT, (void*)(C + (size_t)m0 * 1024), As, Bs);
}

// Wo GEMM: 64x128 tiles -> 512 blocks (2 blocks/CU co-residency).
__global__ __launch_bounds__(256, 4) void gemm_wo_kernel(const _Float16* __restrict__ Ah,
                                                         const _Float16* __restrict__ WoT,
                                                         float* __restrict__ out) {
    __shared__ _Float16 As[64 * 64], Bs[128 * 64];
    int gx = blockIdx.x;
    int m0 = (gx >> 3) * 64, n0 = (gx & 7) * 128;
    gemm_body<64, true>(Ah + (size_t)m0 * 1024, WoT + (size_t)n0 * 1024,
                        (void*)(out + (size_t)m0 * 1024 + n0), As, Bs);
}

// ------------- MFMA flash attention (fixed-max softmax), per (b,g) pair -------------
// R15 == R14 resubmitted (R4 bench was an infra failure; kernel audited clean:
// no OOB, uniform barriers, DMA drained by barrier vmcnt semantics).
// Double-buffered LDS, ONE barrier per chunk, DMA K staging, (512,6) no-spill.
// grid (4 q-blocks, 256 pairs) = 1024 blocks, 512 threads (8 waves).
//  - K staging: global_load_lds DMA (zero VGPRs), waves 0-3; the bit2<->3 key perm
//    is applied to the per-lane GLOBAL source addr, LDS dest stays linear (m173):
//    slot s holds key (s>>6)*32 + perm(s&31), halves ((s>>5)&1)*8  == old kdst map.
//  - V staging: waves 4-7, 4 VGPRs/thread (two f16x4 loads, 4 swizzled ds_write_b32;
//    write banks = (u&3) | ((jj^(u>>2))<<2) -> exactly 2 lanes/bank = free).
//  - Pipeline per chunk: barrier -> issue K-DMA + V loads (next chunk, buf^1) ->
//    compute(buf) -> V ds_writes (write-late, T14) -> next barrier. Staging latency
//    hides under the ~1500cy compute phase; 1 barrier/chunk (was 2).
//  - ones-lane V-reads re-broadcast (offset masked to 0; R3's folded offsets had
//    scattered them -> 4-way read alias, the residual 524K conflicts).
//  - __launch_bounds__(512,6): ~85 VGPR budget ends the chronic 2-dword spill
//    (R2/R3: +2-4MB WRITE_SIZE); 3 blocks/CU, LDS 16.4 KB.
// Wave: 32 queries x 1024 keys, 32 keys/iter:
//   S32 = Khat.Q^T via ONE mfma_32x32x16; Khat row m = physical key perm(m),
//   C-layout regs 0-7 / 8-15, exp'd + packed, ARE the B-frags of two mfma_32x32x16
//   PV calls. PV A rows 0-15 = V^T, rows 16-31 = ones -> L fused into acc regs 8-15.
__global__ __launch_bounds__(512, 6) void attn_kernel(const _Float16* __restrict__ Qh,
                                                      const _Float16* __restrict__ Kh,
                                                      const _Float16* __restrict__ Vh,
                                                      _Float16* __restrict__ Ah) {
    int pair = blockIdx.y;
    int b = pair >> 6, g = pair & 63;
    __shared__ _Float16 KA[4096];    // 2 bufs x [t:4][lane:64][8 halves]
    __shared__ _Float16 VA[4096];    // 2 bufs x [pvblk:8][kb3][head^swz|hi][klow]
    __shared__ _Float16 ones[8];     // broadcast all-1.0 A-frag for L rows

    const _Float16* Kg = Kh + (size_t)(b * 1024) * 1024 + g * 16;
    const _Float16* Vg = Vh + (size_t)(b * 1024) * 1024 + g * 16;
    int tid = threadIdx.x;
    if (tid < 8) ones[tid] = (_Float16)1.f;

    int lane = tid & 63, wave = tid >> 6;    // wave 0..7
    int n = lane & 31, h5 = lane >> 5;       // n = q (S/PV col), also PV A-row m
    int q0 = blockIdx.x * 256 + wave * 32;

    // Q B-frag: B[k=head=h5*8+j][n=q]; fold 0.25*log2(e) -> scores in log2 domain.
    f16x8 qf;
    {
        f16x8 t = *(const f16x8*)(Qh + (size_t)(b * 1024 + q0 + n) * 1024 + g * 16 + h5 * 8);
#pragma unroll
        for (int j = 0; j < 8; j++) qf[j] = (_Float16)((float)t[j] * 0.360673760f);
    }

    f32x16 acc = {0.f, 0.f, 0.f, 0.f, 0.f, 0.f, 0.f, 0.f,
                  0.f, 0.f, 0.f, 0.f, 0.f, 0.f, 0.f, 0.f};
    const f32x16 zero16 = acc;

    // ---- K DMA source (waves 0-3): per-lane pre-permuted global addr ----
    const int pl = lane & 31;
    const int kperm = (pl & 19) | ((pl & 4) << 1) | ((pl & 8) >> 1);   // swap bits 2,3
    const _Float16* ksrc = Kg + (size_t)((wave & 3) * 32 + kperm) * 1024 + (lane >> 5) * 8;
    _Float16* kdst = KA + (wave & 3) * 512;          // + bufsel*2048

    // ---- V staging (waves 4-7): u in [0,256), pair (vk0,vk0+1), 4 heads ----
    const int u = tid & 255;
    const int vk0 = (u & 63) * 2;
    const int hq = u >> 6;                   // head quad 0..3
    const int vpart = hq >> 1, jb = (hq & 1) * 4;
    const _Float16* vsrcA = Vg + (size_t)vk0 * 1024 + vpart * 8 + jb;
    const int vbw3 = ((((vk0 >> 4) * 256) + ((vk0 >> 3) & 1) * 128 + vpart * 64 + (vk0 & 7))
                      ^ (((vk0 >> 3) & 7) << 3)) ^ (jb * 8);

    // ---- compute-side V read: single base reg + folded per-pvblk immediates ----
    // addr(s) = ((vb0 ^ ((s&3)<<4)) | ((s&3)<<8) | ((s>>2)<<10)) & vmask
    const int vb0 = h5 * 128 + ((n & 8) | ((n & 7) ^ h5)) * 8;
    const int vmask = (n < 16) ? -1 : 0;     // ones-lanes: offset 0 -> broadcast
    const _Float16* vrb = (n < 16) ? VA : ones;
    const int vbufstep = (n < 16) ? 2048 : 0;

    // ---- prologue: stage chunk 0 into buf 0 ----
    if (tid < 256) {
        GLOAD_LDS16(ksrc, kdst);
    } else {
        f16x4 va = *(const f16x4*)(vsrcA);
        f16x4 vb = *(const f16x4*)(vsrcA + 1024);
#pragma unroll
        for (int jj = 0; jj < 4; jj++) {
            f16x2 pr; pr[0] = va[jj]; pr[1] = vb[jj];
            *(f16x2*)(VA + (vbw3 ^ (jj * 8))) = pr;
        }
    }

    for (int c = 0; c < 8; c++) {            // 128-key chunks
        __syncthreads();                     // buf[c&1] staged; buf[c&1^1] free
        const int cb = c & 1;
        f16x4 va, vb;
        if (c < 7) {                         // issue next chunk's staging early
            if (tid < 256) {
                GLOAD_LDS16(ksrc + (size_t)((c + 1) * 128) * 1024, kdst + (cb ^ 1) * 2048);
            } else {
                va = *(const f16x4*)(vsrcA + (size_t)((c + 1) * 128) * 1024);
                vb = *(const f16x4*)(vsrcA + (size_t)((c + 1) * 128) * 1024 + 1024);
            }
        }
        const _Float16* akc = KA + cb * 2048;
        const _Float16* vrbc = vrb + cb * vbufstep;

        __builtin_amdgcn_s_setprio(1);
#pragma unroll
        for (int t = 0; t < 4; t++) {        // 32 keys per iteration
            f16x8 ak = *(const f16x8*)(akc + (t * 64 + lane) * 8);
            f32x16 s = __builtin_amdgcn_mfma_f32_32x32x16_f16(ak, qf, zero16, 0, 0, 0);
            float p[16];
#pragma unroll
            for (int i = 0; i < 16; i++) p[i] = __builtin_amdgcn_exp2f(s[i]);
            f16x8 pb0 = pack8f(p);           // keys t*32 + 0..15  (k=h5*8+j)
            f16x8 pb1 = pack8f(p + 8);       // keys t*32 + 16..31
            const int o0 = ((vb0 ^ (((2 * t) & 3) << 4)) | (((2 * t) & 3) << 8)
                            | (((2 * t) >> 2) << 10)) & vmask;
            const int o1 = ((vb0 ^ (((2 * t + 1) & 3) << 4)) | (((2 * t + 1) & 3) << 8)
                            | (((2 * t + 1) >> 2) << 10)) & vmask;
            f16x8 av0 = *(const f16x8*)(vrbc + o0);
            f16x8 av1 = *(const f16x8*)(vrbc + o1);
            acc = __builtin_amdgcn_mfma_f32_32x32x16_f16(av0, pb0, acc, 0, 0, 0);
            acc = __builtin_amdgcn_mfma_f32_32x32x16_f16(av1, pb1, acc, 0, 0, 0);
        }
        __builtin_amdgcn_s_setprio(0);

        if (c < 7 && tid >= 256) {           // write-late: V regs -> buf^1
#pragma unroll
            for (int jj = 0; jj < 4; jj++) {
                f16x2 pr; pr[0] = va[jj]; pr[1] = vb[jj];
                *(f16x2*)(VA + (cb ^ 1) * 2048 + (vbw3 ^ (jj * 8))) = pr;
            }
        }
    }

    // acc C-layout: col q=n; regs 0-7 -> heads, regs 8-15 -> L (all equal = key-sum).
    float rl = 1.0f / acc[8];
    f16x4 o0, o1;
#pragma unroll
    for (int i = 0; i < 4; i++) o0[i] = (_Float16)(acc[i] * rl);       // heads 4*h5+0..3
#pragma unroll
    for (int i = 0; i < 4; i++) o1[i] = (_Float16)(acc[4 + i] * rl);   // heads 4*h5+8..11
    _Float16* ob = Ah + (size_t)(b * 1024 + q0 + n) * 1024 + g * 16 + h5 * 4;
    *(f16x4*)(ob) = o0;
    *(f16x4*)(ob + 8) = o1;
}

extern "C" void kernel_launch(void* const* d_in, const int* in_sizes, int n_in,
                              void* d_out, int out_size, void* d_ws, size_t ws_size,
                              hipStream_t stream) {
    const float* x1 = (const float*)d_in[0];
    const float* x2 = (const float*)d_in[1];
    const float* Wq = (const float*)d_in[2];
    const float* Wk = (const float*)d_in[3];
    const float* Wv = (const float*)d_in[4];
    const float* Wo = (const float*)d_in[5];

    char* ws = (char*)d_ws;
    const size_t MB = 1u << 20;
    if (ws_size < 56 * MB) return;

    _Float16* x1h = (_Float16*)(ws + 0 * MB);   // 4096x1024
    _Float16* x2h = (_Float16*)(ws + 8 * MB);   // 4096x1024
    _Float16* WqT = (_Float16*)(ws + 16 * MB);  // 1024x1024 (N,K)
    _Float16* WkT = (_Float16*)(ws + 18 * MB);  // contiguous with WvT -> stacked (2048,1024)
    _Float16* WvT = (_Float16*)(ws + 20 * MB);
    _Float16* WoT = (_Float16*)(ws + 22 * MB);
    _Float16* Qh  = (_Float16*)(ws + 24 * MB);  // 4096x1024
    _Float16* Kh  = (_Float16*)(ws + 32 * MB);
    _Float16* Vh  = (_Float16*)(ws + 40 * MB);
    _Float16* Ah  = (_Float16*)(ws + 48 * MB);

    prep_kernel<<<12288, 256, 0, stream>>>(x1, x2, Wq, Wk, Wv, Wo,
                                           x1h, x2h, WqT, WkT, WvT, WoT);

    gemm_qkv_kernel<<<768, 256, 0, stream>>>(x1h, x2h, WqT, WkT, Qh, Kh, Vh);

    attn_kernel<<<dim3(4, 256), 512, 0, stream>>>(Qh, Kh, Vh, Ah);

    gemm_wo_kernel<<<512, 256, 0, stream>>>(Ah, WoT, (float*)d_out);
}

// Round 6
// 185.918 us; speedup vs baseline: 1.0332x; 1.0332x over previous
//
#include <hip/hip_runtime.h>

// B=4, C=C2=1024, E=1024, D=1024, NH(head dim)=16, G=64 groups. Rows B*C=4096.

typedef _Float16 f16x8 __attribute__((ext_vector_type(8)));
typedef _Float16 f16x4 __attribute__((ext_vector_type(4)));
typedef _Float16 f16x2 __attribute__((ext_vector_type(2)));
typedef float    f32x4 __attribute__((ext_vector_type(4)));
typedef float    f32x16 __attribute__((ext_vector_type(16)));

// global -> LDS direct DMA, 16 B per lane. LDS dest = wave-uniform base + lane*16.
#define GLOAD_LDS16(gp, lp)                                              \
    __builtin_amdgcn_global_load_lds(                                    \
        (const __attribute__((address_space(1))) void*)(gp),             \
        (__attribute__((address_space(3))) void*)(lp), 16, 0, 0)

static __device__ __forceinline__ f16x8 pack8f(const float* p) {
    f16x2 a = __builtin_bit_cast(f16x2, __builtin_amdgcn_cvt_pkrtz(p[0], p[1]));
    f16x2 b = __builtin_bit_cast(f16x2, __builtin_amdgcn_cvt_pkrtz(p[2], p[3]));
    f16x2 c = __builtin_bit_cast(f16x2, __builtin_amdgcn_cvt_pkrtz(p[4], p[5]));
    f16x2 d = __builtin_bit_cast(f16x2, __builtin_amdgcn_cvt_pkrtz(p[6], p[7]));
    f16x8 r;
    r[0] = a[0]; r[1] = a[1]; r[2] = b[0]; r[3] = b[1];
    r[4] = c[0]; r[5] = c[1]; r[6] = d[0]; r[7] = d[1];
    return r;
}

// ---- prep: fp32->fp16 convert of x1,x2 (blocks 0..8191) + transpose-convert of the
// ---- 4 weights into (N,K) f16 (blocks 8192..12287), one launch ----
__global__ __launch_bounds__(256) void prep_kernel(
        const float* __restrict__ x1, const float* __restrict__ x2,
        const float* __restrict__ W0, const float* __restrict__ W1,
        const float* __restrict__ W2, const float* __restrict__ W3,
        _Float16* __restrict__ y1, _Float16* __restrict__ y2,
        _Float16* __restrict__ T0, _Float16* __restrict__ T1,
        _Float16* __restrict__ T2, _Float16* __restrict__ T3) {
    int bx = blockIdx.x, tid = threadIdx.x;
    if (bx < 8192) {
        int i = bx * 256 + tid;              // 2M float4 total
        const float* x = (i < 1048576) ? x1 : x2;
        _Float16* y = (i < 1048576) ? y1 : y2;
        int j = i & 1048575;
        float4 v = ((const float4*)x)[j];
        f16x4 h = { (_Float16)v.x, (_Float16)v.y, (_Float16)v.z, (_Float16)v.w };
        ((f16x4*)y)[j] = h;
    } else {
        int z = (bx - 8192) >> 10;
        const float* W = (z == 0) ? W0 : (z == 1) ? W1 : (z == 2) ? W2 : W3;
        _Float16* WT = (z == 0) ? T0 : (z == 1) ? T1 : (z == 2) ? T2 : T3;
        int t = (bx - 8192) & 1023;
        int c0 = (t & 31) * 32, r0 = (t >> 5) * 32;
        __shared__ float tile[32][33];
        int tx = tid & 31, ty = tid >> 5;    // 32 x 8
#pragma unroll
        for (int i = 0; i < 32; i += 8)
            tile[ty + i][tx] = W[(r0 + ty + i) * 1024 + (c0 + tx)];
        __syncthreads();
#pragma unroll
        for (int i = 0; i < 32; i += 8)
            WT[(c0 + ty + i) * 1024 + (r0 + tx)] = (_Float16)tile[tx][ty + i];
    }
}

// ------------- m97-style MTx128 GEMM body (pre-offset pointers, K=1024) -------------
// block 256 (4 waves, 2x2 over MT x 128), BK=64, global_load_lds w16, 16x16x32 MFMA.
template <int MT, bool OUTF32>
static __device__ __forceinline__ void gemm_body(const _Float16* __restrict__ Atile,
                                                 const _Float16* __restrict__ BTtile,
                                                 void* __restrict__ Ctile,
                                                 _Float16* As, _Float16* Bs) {
    constexpr int AF = MT / 32;              // A staging rounds & m-frags per wave
    const int tid = threadIdx.x, lane = tid & 63, wave = tid >> 6;
    const int wm = wave >> 1, wn = wave & 1;
    const int col = lane & 15, quad = lane >> 4;

    f32x4 acc[AF][4];
#pragma unroll
    for (int i = 0; i < AF; i++)
#pragma unroll
        for (int j = 0; j < 4; j++) acc[i][j] = (f32x4){0.f, 0.f, 0.f, 0.f};

    const int srow = wave * 8 + (lane >> 3);
    const int sch = (lane & 7) * 8;
    const _Float16* Ag = Atile + (size_t)srow * 1024 + sch;
    const _Float16* Bg = BTtile + (size_t)srow * 1024 + sch;
    _Float16* Asl = As + wave * 512;
    _Float16* Bsl = Bs + wave * 512;

    for (int kt = 0; kt < 16; kt++) {
        __syncthreads();
#pragma unroll
        for (int c = 0; c < AF; c++)
            GLOAD_LDS16(Ag + (size_t)(c * 32) * 1024 + kt * 64, Asl + c * 2048);
#pragma unroll
        for (int c = 0; c < 4; c++)
            GLOAD_LDS16(Bg + (size_t)(c * 32) * 1024 + kt * 64, Bsl + c * 2048);
        __syncthreads();
#pragma unroll
        for (int ki = 0; ki < 2; ki++) {
            f16x8 af[AF], bf[4];
#pragma unroll
            for (int i = 0; i < AF; i++)
                af[i] = *(const f16x8*)(As + (wm * (MT / 2) + i * 16 + col) * 64 + ki * 32 + quad * 8);
#pragma unroll
            for (int j = 0; j < 4; j++)
                bf[j] = *(const f16x8*)(Bs + (wn * 64 + j * 16 + col) * 64 + ki * 32 + quad * 8);
#pragma unroll
            for (int i = 0; i < AF; i++)
#pragma unroll
                for (int j = 0; j < 4; j++)
                    acc[i][j] = __builtin_amdgcn_mfma_f32_16x16x32_f16(af[i], bf[j], acc[i][j], 0, 0, 0);
        }
    }

#pragma unroll
    for (int i = 0; i < AF; i++)
#pragma unroll
        for (int ii = 0; ii < 4; ii++) {
            int row = wm * (MT / 2) + i * 16 + quad * 4 + ii;
#pragma unroll
            for (int j = 0; j < 4; j++) {
                int cc = wn * 64 + j * 16 + col;
                if (OUTF32) ((float*)Ctile)[(size_t)row * 1024 + cc] = acc[i][j][ii];
                else ((_Float16*)Ctile)[(size_t)row * 1024 + cc] = (_Float16)acc[i][j][ii];
            }
        }
}

// Fused Q + (KV as N=2048) projections, flat 768-block grid (128x128 tiles):
__global__ __launch_bounds__(256, 3) void gemm_qkv_kernel(
        const _Float16* __restrict__ x1h, const _Float16* __restrict__ x2h,
        const _Float16* __restrict__ WqT, const _Float16* __restrict__ WkvT,
        _Float16* __restrict__ Qh, _Float16* __restrict__ Kh, _Float16* __restrict__ Vh) {
    __shared__ _Float16 As[128 * 64], Bs[128 * 64];
    int gx = blockIdx.x;
    const _Float16 *A, *BT;
    _Float16* C;
    int m0, n0;
    if (gx < 256) {
        m0 = (gx >> 3) * 128; n0 = (gx & 7) * 128;
        A = x1h; BT = WqT + (size_t)n0 * 1024; C = Qh + n0;
    } else {
        int idx = gx - 256;
        m0 = (idx >> 4) * 128;
        int nb = idx & 15;
        n0 = nb * 128;                        // 0..2047 within stacked KV
        A = x2h; BT = WkvT + (size_t)n0 * 1024;
        C = (nb < 8) ? (Kh + n0) : (Vh + (n0 - 1024));
    }
    gemm_body<128, false>(A + (size_t)m0 * 1024, BT, (void*)(C + (size_t)m0 * 1024), As, Bs);
}

// Wo GEMM: 64x128 tiles -> 512 blocks (2 blocks/CU co-residency).
__global__ __launch_bounds__(256, 4) void gemm_wo_kernel(const _Float16* __restrict__ Ah,
                                                         const _Float16* __restrict__ WoT,
                                                         float* __restrict__ out) {
    __shared__ _Float16 As[64 * 64], Bs[128 * 64];
    int gx = blockIdx.x;
    int m0 = (gx >> 3) * 64, n0 = (gx & 7) * 128;
    gemm_body<64, true>(Ah + (size_t)m0 * 1024, WoT + (size_t)n0 * 1024,
                        (void*)(out + (size_t)m0 * 1024 + n0), As, Bs);
}

// ------------- MFMA flash attention (fixed-max softmax), per (b,g) pair -------------
// R16 = R15 + XCD-coherent work swizzle (single change, clean attribution).
// Evidence (R15): FETCH 73.8 MB vs 16 MB unique K/V (4.5x HBM re-read); per-chunk
// compute phase (~600cy) < cold-HBM staging latency (~900cy) -> barrier waits on
// memory every chunk (VALUBusy 45%, occupancy-stalled). Cause: pairs (b,2j),(b,2j+1)
// share every 64B K/V line, and 4 q-chunk blocks re-read each slice; linear id
// q+4*pair makes id%8 (XCD) mix q and g -> sharers on different XCD L2s.
// Fix: linear grid 1024; L -> {x=L&7, y=L>>3}; halfpid=x+8*(y&15);
// pid=2*halfpid|((y>>4)&1); qchunk=y>>5.  All 8 sharers of a line family
// (2 g x 4 q) have the same L%8 -> same XCD; per-XCD K/V working set =
// 16 halfpids x 128 KB = 2 MB < 4 MB L2, zero line waste -> staging becomes
// L2-hit (~200cy), hidden under compute.
// Structure (unchanged from R15): double-buffered LDS, ONE barrier per chunk,
// DMA K staging (pre-permuted global addrs, linear LDS dest), V staged by waves
// 4-7 (swizzled ds_write_b32, 2 lanes/bank), write-late, (512,6), setprio.
__global__ __launch_bounds__(512, 6) void attn_kernel(const _Float16* __restrict__ Qh,
                                                      const _Float16* __restrict__ Kh,
                                                      const _Float16* __restrict__ Vh,
                                                      _Float16* __restrict__ Ah) {
    // ---- XCD-coherent swizzle ----
    int L = blockIdx.x;                      // 0..1023
    int xcd = L & 7, y = L >> 3;             // HW: XCD ~= L%8 (round-robin)
    int halfpid = xcd + ((y & 15) << 3);     // 0..127, fixed per XCD
    int pid = (halfpid << 1) | ((y >> 4) & 1);
    int qch = y >> 5;                        // 0..3
    int b = pid >> 6, g = pid & 63;

    __shared__ _Float16 KA[4096];    // 2 bufs x [t:4][lane:64][8 halves]
    __shared__ _Float16 VA[4096];    // 2 bufs x [pvblk:8][kb3][head^swz|hi][klow]
    __shared__ _Float16 ones[8];     // broadcast all-1.0 A-frag for L rows

    const _Float16* Kg = Kh + (size_t)(b * 1024) * 1024 + g * 16;
    const _Float16* Vg = Vh + (size_t)(b * 1024) * 1024 + g * 16;
    int tid = threadIdx.x;
    if (tid < 8) ones[tid] = (_Float16)1.f;

    int lane = tid & 63, wave = tid >> 6;    // wave 0..7
    int n = lane & 31, h5 = lane >> 5;       // n = q (S/PV col), also PV A-row m
    int q0 = qch * 256 + wave * 32;

    // Q B-frag: B[k=head=h5*8+j][n=q]; fold 0.25*log2(e) -> scores in log2 domain.
    f16x8 qf;
    {
        f16x8 t = *(const f16x8*)(Qh + (size_t)(b * 1024 + q0 + n) * 1024 + g * 16 + h5 * 8);
#pragma unroll
        for (int j = 0; j < 8; j++) qf[j] = (_Float16)((float)t[j] * 0.360673760f);
    }

    f32x16 acc = {0.f, 0.f, 0.f, 0.f, 0.f, 0.f, 0.f, 0.f,
                  0.f, 0.f, 0.f, 0.f, 0.f, 0.f, 0.f, 0.f};
    const f32x16 zero16 = acc;

    // ---- K DMA source (waves 0-3): per-lane pre-permuted global addr ----
    const int pl = lane & 31;
    const int kperm = (pl & 19) | ((pl & 4) << 1) | ((pl & 8) >> 1);   // swap bits 2,3
    const _Float16* ksrc = Kg + (size_t)((wave & 3) * 32 + kperm) * 1024 + (lane >> 5) * 8;
    _Float16* kdst = KA + (wave & 3) * 512;          // + bufsel*2048

    // ---- V staging (waves 4-7): u in [0,256), pair (vk0,vk0+1), 4 heads ----
    const int u = tid & 255;
    const int vk0 = (u & 63) * 2;
    const int hq = u >> 6;                   // head quad 0..3
    const int vpart = hq >> 1, jb = (hq & 1) * 4;
    const _Float16* vsrcA = Vg + (size_t)vk0 * 1024 + vpart * 8 + jb;
    const int vbw3 = ((((vk0 >> 4) * 256) + ((vk0 >> 3) & 1) * 128 + vpart * 64 + (vk0 & 7))
                      ^ (((vk0 >> 3) & 7) << 3)) ^ (jb * 8);

    // ---- compute-side V read: single base reg + folded per-pvblk immediates ----
    // addr(s) = ((vb0 ^ ((s&3)<<4)) | ((s&3)<<8) | ((s>>2)<<10)) & vmask
    const int vb0 = h5 * 128 + ((n & 8) | ((n & 7) ^ h5)) * 8;
    const int vmask = (n < 16) ? -1 : 0;     // ones-lanes: offset 0 -> broadcast
    const _Float16* vrb = (n < 16) ? VA : ones;
    const int vbufstep = (n < 16) ? 2048 : 0;

    // ---- prologue: stage chunk 0 into buf 0 ----
    if (tid < 256) {
        GLOAD_LDS16(ksrc, kdst);
    } else {
        f16x4 va = *(const f16x4*)(vsrcA);
        f16x4 vb = *(const f16x4*)(vsrcA + 1024);
#pragma unroll
        for (int jj = 0; jj < 4; jj++) {
            f16x2 pr; pr[0] = va[jj]; pr[1] = vb[jj];
            *(f16x2*)(VA + (vbw3 ^ (jj * 8))) = pr;
        }
    }

    for (int c = 0; c < 8; c++) {            // 128-key chunks
        __syncthreads();                     // buf[c&1] staged; buf[c&1^1] free
        const int cb = c & 1;
        f16x4 va, vb;
        if (c < 7) {                         // issue next chunk's staging early
            if (tid < 256) {
                GLOAD_LDS16(ksrc + (size_t)((c + 1) * 128) * 1024, kdst + (cb ^ 1) * 2048);
            } else {
                va = *(const f16x4*)(vsrcA + (size_t)((c + 1) * 128) * 1024);
                vb = *(const f16x4*)(vsrcA + (size_t)((c + 1) * 128) * 1024 + 1024);
            }
        }
        const _Float16* akc = KA + cb * 2048;
        const _Float16* vrbc = vrb + cb * vbufstep;

        __builtin_amdgcn_s_setprio(1);
#pragma unroll
        for (int t = 0; t < 4; t++) {        // 32 keys per iteration
            f16x8 ak = *(const f16x8*)(akc + (t * 64 + lane) * 8);
            f32x16 s = __builtin_amdgcn_mfma_f32_32x32x16_f16(ak, qf, zero16, 0, 0, 0);
            float p[16];
#pragma unroll
            for (int i = 0; i < 16; i++) p[i] = __builtin_amdgcn_exp2f(s[i]);
            f16x8 pb0 = pack8f(p);           // keys t*32 + 0..15  (k=h5*8+j)
            f16x8 pb1 = pack8f(p + 8);       // keys t*32 + 16..31
            const int o0 = ((vb0 ^ (((2 * t) & 3) << 4)) | (((2 * t) & 3) << 8)
                            | (((2 * t) >> 2) << 10)) & vmask;
            const int o1 = ((vb0 ^ (((2 * t + 1) & 3) << 4)) | (((2 * t + 1) & 3) << 8)
                            | (((2 * t + 1) >> 2) << 10)) & vmask;
            f16x8 av0 = *(const f16x8*)(vrbc + o0);
            f16x8 av1 = *(const f16x8*)(vrbc + o1);
            acc = __builtin_amdgcn_mfma_f32_32x32x16_f16(av0, pb0, acc, 0, 0, 0);
            acc = __builtin_amdgcn_mfma_f32_32x32x16_f16(av1, pb1, acc, 0, 0, 0);
        }
        __builtin_amdgcn_s_setprio(0);

        if (c < 7 && tid >= 256) {           // write-late: V regs -> buf^1
#pragma unroll
            for (int jj = 0; jj < 4; jj++) {
                f16x2 pr; pr[0] = va[jj]; pr[1] = vb[jj];
                *(f16x2*)(VA + (cb ^ 1) * 2048 + (vbw3 ^ (jj * 8))) = pr;
            }
        }
    }

    // acc C-layout: col q=n; regs 0-7 -> heads, regs 8-15 -> L (all equal = key-sum).
    float rl = 1.0f / acc[8];
    f16x4 o0, o1;
#pragma unroll
    for (int i = 0; i < 4; i++) o0[i] = (_Float16)(acc[i] * rl);       // heads 4*h5+0..3
#pragma unroll
    for (int i = 0; i < 4; i++) o1[i] = (_Float16)(acc[4 + i] * rl);   // heads 4*h5+8..11
    _Float16* ob = Ah + (size_t)(b * 1024 + q0 + n) * 1024 + g * 16 + h5 * 4;
    *(f16x4*)(ob) = o0;
    *(f16x4*)(ob + 8) = o1;
}

extern "C" void kernel_launch(void* const* d_in, const int* in_sizes, int n_in,
                              void* d_out, int out_size, void* d_ws, size_t ws_size,
                              hipStream_t stream) {
    const float* x1 = (const float*)d_in[0];
    const float* x2 = (const float*)d_in[1];
    const float* Wq = (const float*)d_in[2];
    const float* Wk = (const float*)d_in[3];
    const float* Wv = (const float*)d_in[4];
    const float* Wo = (const float*)d_in[5];

    char* ws = (char*)d_ws;
    const size_t MB = 1u << 20;
    if (ws_size < 56 * MB) return;

    _Float16* x1h = (_Float16*)(ws + 0 * MB);   // 4096x1024
    _Float16* x2h = (_Float16*)(ws + 8 * MB);   // 4096x1024
    _Float16* WqT = (_Float16*)(ws + 16 * MB);  // 1024x1024 (N,K)
    _Float16* WkT = (_Float16*)(ws + 18 * MB);  // contiguous with WvT -> stacked (2048,1024)
    _Float16* WvT = (_Float16*)(ws + 20 * MB);
    _Float16* WoT = (_Float16*)(ws + 22 * MB);
    _Float16* Qh  = (_Float16*)(ws + 24 * MB);  // 4096x1024
    _Float16* Kh  = (_Float16*)(ws + 32 * MB);
    _Float16* Vh  = (_Float16*)(ws + 40 * MB);
    _Float16* Ah  = (_Float16*)(ws + 48 * MB);

    prep_kernel<<<12288, 256, 0, stream>>>(x1, x2, Wq, Wk, Wv, Wo,
                                           x1h, x2h, WqT, WkT, WvT, WoT);

    gemm_qkv_kernel<<<768, 256, 0, stream>>>(x1h, x2h, WqT, WkT, Qh, Kh, Vh);

    attn_kernel<<<1024, 512, 0, stream>>>(Qh, Kh, Vh, Ah);

    gemm_wo_kernel<<<512, 256, 0, stream>>>(Ah, WoT, (float*)d_out);
}

// Round 7
// 179.204 us; speedup vs baseline: 1.0720x; 1.0375x over previous
//
#include <hip/hip_runtime.h>

// B=4, C=C2=1024, E=1024, D=1024, NH(head dim)=16, G=64 groups. Rows B*C=4096.

typedef _Float16 f16x8 __attribute__((ext_vector_type(8)));
typedef _Float16 f16x4 __attribute__((ext_vector_type(4)));
typedef _Float16 f16x2 __attribute__((ext_vector_type(2)));
typedef float    f32x4 __attribute__((ext_vector_type(4)));
typedef float    f32x16 __attribute__((ext_vector_type(16)));

// global -> LDS direct DMA, 16 B per lane. LDS dest = wave-uniform base + lane*16.
#define GLOAD_LDS16(gp, lp)                                              \
    __builtin_amdgcn_global_load_lds(                                    \
        (const __attribute__((address_space(1))) void*)(gp),             \
        (__attribute__((address_space(3))) void*)(lp), 16, 0, 0)

static __device__ __forceinline__ f16x8 pack8f(const float* p) {
    f16x2 a = __builtin_bit_cast(f16x2, __builtin_amdgcn_cvt_pkrtz(p[0], p[1]));
    f16x2 b = __builtin_bit_cast(f16x2, __builtin_amdgcn_cvt_pkrtz(p[2], p[3]));
    f16x2 c = __builtin_bit_cast(f16x2, __builtin_amdgcn_cvt_pkrtz(p[4], p[5]));
    f16x2 d = __builtin_bit_cast(f16x2, __builtin_amdgcn_cvt_pkrtz(p[6], p[7]));
    f16x8 r;
    r[0] = a[0]; r[1] = a[1]; r[2] = b[0]; r[3] = b[1];
    r[4] = c[0]; r[5] = c[1]; r[6] = d[0]; r[7] = d[1];
    return r;
}

// ---- prep: fp32->fp16 convert of x1,x2 (blocks 0..8191) + transpose-convert of the
// ---- 4 weights into (N,K) f16 (blocks 8192..12287), one launch ----
__global__ __launch_bounds__(256) void prep_kernel(
        const float* __restrict__ x1, const float* __restrict__ x2,
        const float* __restrict__ W0, const float* __restrict__ W1,
        const float* __restrict__ W2, const float* __restrict__ W3,
        _Float16* __restrict__ y1, _Float16* __restrict__ y2,
        _Float16* __restrict__ T0, _Float16* __restrict__ T1,
        _Float16* __restrict__ T2, _Float16* __restrict__ T3) {
    int bx = blockIdx.x, tid = threadIdx.x;
    if (bx < 8192) {
        int i = bx * 256 + tid;              // 2M float4 total
        const float* x = (i < 1048576) ? x1 : x2;
        _Float16* y = (i < 1048576) ? y1 : y2;
        int j = i & 1048575;
        float4 v = ((const float4*)x)[j];
        f16x4 h = { (_Float16)v.x, (_Float16)v.y, (_Float16)v.z, (_Float16)v.w };
        ((f16x4*)y)[j] = h;
    } else {
        int z = (bx - 8192) >> 10;
        const float* W = (z == 0) ? W0 : (z == 1) ? W1 : (z == 2) ? W2 : W3;
        _Float16* WT = (z == 0) ? T0 : (z == 1) ? T1 : (z == 2) ? T2 : T3;
        int t = (bx - 8192) & 1023;
        int c0 = (t & 31) * 32, r0 = (t >> 5) * 32;
        __shared__ float tile[32][33];
        int tx = tid & 31, ty = tid >> 5;    // 32 x 8
#pragma unroll
        for (int i = 0; i < 32; i += 8)
            tile[ty + i][tx] = W[(r0 + ty + i) * 1024 + (c0 + tx)];
        __syncthreads();
#pragma unroll
        for (int i = 0; i < 32; i += 8)
            WT[(c0 + ty + i) * 1024 + (r0 + tx)] = (_Float16)tile[tx][ty + i];
    }
}

// ------------- m97-style MTx128 GEMM body (pre-offset pointers, K=1024) -------------
// block 256 (4 waves, 2x2 over MT x 128), BK=64, global_load_lds w16, 16x16x32 MFMA.
// R17: T2-style LDS XOR-swizzle, both-sides (rule #21). Evidence (R6): 9.4M
// SQ_LDS_BANK_CONFLICT cycles/dispatch = 37% of gemm_qkv time; rows stride 128B and
// fragment reads use col=lane&15 as the ROW selector with slot bits fixed per
// (ki,quad) -> 16-way conflict. Fix: DMA dest stays linear; the global SOURCE column
// is pre-swizzled (slot s of row r holds linear column s^(r&7); r&7 == lane>>3 at
// staging), and reads XOR the same involution (row&7 == col&7 at read): half-index
// ^= (col&7)*8. New per-lane slot = (ki*4+quad)^(col&7): 8 distinct slots per 8
// lanes -> 2-way alias (free). Permutation stays inside each 128B line -> global
// coalescing unchanged.
template <int MT, bool OUTF32>
static __device__ __forceinline__ void gemm_body(const _Float16* __restrict__ Atile,
                                                 const _Float16* __restrict__ BTtile,
                                                 void* __restrict__ Ctile,
                                                 _Float16* As, _Float16* Bs) {
    constexpr int AF = MT / 32;              // A staging rounds & m-frags per wave
    const int tid = threadIdx.x, lane = tid & 63, wave = tid >> 6;
    const int wm = wave >> 1, wn = wave & 1;
    const int col = lane & 15, quad = lane >> 4;

    f32x4 acc[AF][4];
#pragma unroll
    for (int i = 0; i < AF; i++)
#pragma unroll
        for (int j = 0; j < 4; j++) acc[i][j] = (f32x4){0.f, 0.f, 0.f, 0.f};

    const int srow = wave * 8 + (lane >> 3);
    // swizzled source column: slot (lane&7) of row (..|lane>>3) holds col slot^(r&7)
    const int sch = ((lane & 7) ^ (lane >> 3)) * 8;
    const _Float16* Ag = Atile + (size_t)srow * 1024 + sch;
    const _Float16* Bg = BTtile + (size_t)srow * 1024 + sch;
    _Float16* Asl = As + wave * 512;
    _Float16* Bsl = Bs + wave * 512;

    const int rsw = (col & 7) * 8;           // read-side XOR (row&7 == col&7)

    for (int kt = 0; kt < 16; kt++) {
        __syncthreads();
#pragma unroll
        for (int c = 0; c < AF; c++)
            GLOAD_LDS16(Ag + (size_t)(c * 32) * 1024 + kt * 64, Asl + c * 2048);
#pragma unroll
        for (int c = 0; c < 4; c++)
            GLOAD_LDS16(Bg + (size_t)(c * 32) * 1024 + kt * 64, Bsl + c * 2048);
        __syncthreads();
#pragma unroll
        for (int ki = 0; ki < 2; ki++) {
            f16x8 af[AF], bf[4];
#pragma unroll
            for (int i = 0; i < AF; i++)
                af[i] = *(const f16x8*)(As + (((wm * (MT / 2) + i * 16 + col) * 64
                                               + ki * 32 + quad * 8) ^ rsw));
#pragma unroll
            for (int j = 0; j < 4; j++)
                bf[j] = *(const f16x8*)(Bs + (((wn * 64 + j * 16 + col) * 64
                                               + ki * 32 + quad * 8) ^ rsw));
#pragma unroll
            for (int i = 0; i < AF; i++)
#pragma unroll
                for (int j = 0; j < 4; j++)
                    acc[i][j] = __builtin_amdgcn_mfma_f32_16x16x32_f16(af[i], bf[j], acc[i][j], 0, 0, 0);
        }
    }

#pragma unroll
    for (int i = 0; i < AF; i++)
#pragma unroll
        for (int ii = 0; ii < 4; ii++) {
            int row = wm * (MT / 2) + i * 16 + quad * 4 + ii;
#pragma unroll
            for (int j = 0; j < 4; j++) {
                int cc = wn * 64 + j * 16 + col;
                if (OUTF32) ((float*)Ctile)[(size_t)row * 1024 + cc] = acc[i][j][ii];
                else ((_Float16*)Ctile)[(size_t)row * 1024 + cc] = (_Float16)acc[i][j][ii];
            }
        }
}

// Fused Q + (KV as N=2048) projections, flat 768-block grid (128x128 tiles):
__global__ __launch_bounds__(256, 3) void gemm_qkv_kernel(
        const _Float16* __restrict__ x1h, const _Float16* __restrict__ x2h,
        const _Float16* __restrict__ WqT, const _Float16* __restrict__ WkvT,
        _Float16* __restrict__ Qh, _Float16* __restrict__ Kh, _Float16* __restrict__ Vh) {
    __shared__ _Float16 As[128 * 64], Bs[128 * 64];
    int gx = blockIdx.x;
    const _Float16 *A, *BT;
    _Float16* C;
    int m0, n0;
    if (gx < 256) {
        m0 = (gx >> 3) * 128; n0 = (gx & 7) * 128;
        A = x1h; BT = WqT + (size_t)n0 * 1024; C = Qh + n0;
    } else {
        int idx = gx - 256;
        m0 = (idx >> 4) * 128;
        int nb = idx & 15;
        n0 = nb * 128;                        // 0..2047 within stacked KV
        A = x2h; BT = WkvT + (size_t)n0 * 1024;
        C = (nb < 8) ? (Kh + n0) : (Vh + (n0 - 1024));
    }
    gemm_body<128, false>(A + (size_t)m0 * 1024, BT, (void*)(C + (size_t)m0 * 1024), As, Bs);
}

// Wo GEMM: 64x128 tiles -> 512 blocks (2 blocks/CU co-residency).
__global__ __launch_bounds__(256, 4) void gemm_wo_kernel(const _Float16* __restrict__ Ah,
                                                         const _Float16* __restrict__ WoT,
                                                         float* __restrict__ out) {
    __shared__ _Float16 As[64 * 64], Bs[128 * 64];
    int gx = blockIdx.x;
    int m0 = (gx >> 3) * 64, n0 = (gx & 7) * 128;
    gemm_body<64, true>(Ah + (size_t)m0 * 1024, WoT + (size_t)n0 * 1024,
                        (void*)(out + (size_t)m0 * 1024 + n0), As, Bs);
}

// ------------- MFMA flash attention (fixed-max softmax), per (b,g) pair -------------
// R16 structure (unchanged this round): XCD-coherent swizzle (FETCH 74->39 MB
// verified), double-buffered LDS, ONE barrier per chunk, DMA K staging (pre-permuted
// global addrs, linear LDS dest), V staged by waves 4-7 (swizzled ds_write_b32,
// 2 lanes/bank), write-late, (512,6), setprio.
__global__ __launch_bounds__(512, 6) void attn_kernel(const _Float16* __restrict__ Qh,
                                                      const _Float16* __restrict__ Kh,
                                                      const _Float16* __restrict__ Vh,
                                                      _Float16* __restrict__ Ah) {
    // ---- XCD-coherent swizzle ----
    int L = blockIdx.x;                      // 0..1023
    int xcd = L & 7, y = L >> 3;             // HW: XCD ~= L%8 (round-robin)
    int halfpid = xcd + ((y & 15) << 3);     // 0..127, fixed per XCD
    int pid = (halfpid << 1) | ((y >> 4) & 1);
    int qch = y >> 5;                        // 0..3
    int b = pid >> 6, g = pid & 63;

    __shared__ _Float16 KA[4096];    // 2 bufs x [t:4][lane:64][8 halves]
    __shared__ _Float16 VA[4096];    // 2 bufs x [pvblk:8][kb3][head^swz|hi][klow]
    __shared__ _Float16 ones[8];     // broadcast all-1.0 A-frag for L rows

    const _Float16* Kg = Kh + (size_t)(b * 1024) * 1024 + g * 16;
    const _Float16* Vg = Vh + (size_t)(b * 1024) * 1024 + g * 16;
    int tid = threadIdx.x;
    if (tid < 8) ones[tid] = (_Float16)1.f;

    int lane = tid & 63, wave = tid >> 6;    // wave 0..7
    int n = lane & 31, h5 = lane >> 5;       // n = q (S/PV col), also PV A-row m
    int q0 = qch * 256 + wave * 32;

    // Q B-frag: B[k=head=h5*8+j][n=q]; fold 0.25*log2(e) -> scores in log2 domain.
    f16x8 qf;
    {
        f16x8 t = *(const f16x8*)(Qh + (size_t)(b * 1024 + q0 + n) * 1024 + g * 16 + h5 * 8);
#pragma unroll
        for (int j = 0; j < 8; j++) qf[j] = (_Float16)((float)t[j] * 0.360673760f);
    }

    f32x16 acc = {0.f, 0.f, 0.f, 0.f, 0.f, 0.f, 0.f, 0.f,
                  0.f, 0.f, 0.f, 0.f, 0.f, 0.f, 0.f, 0.f};
    const f32x16 zero16 = acc;

    // ---- K DMA source (waves 0-3): per-lane pre-permuted global addr ----
    const int pl = lane & 31;
    const int kperm = (pl & 19) | ((pl & 4) << 1) | ((pl & 8) >> 1);   // swap bits 2,3
    const _Float16* ksrc = Kg + (size_t)((wave & 3) * 32 + kperm) * 1024 + (lane >> 5) * 8;
    _Float16* kdst = KA + (wave & 3) * 512;          // + bufsel*2048

    // ---- V staging (waves 4-7): u in [0,256), pair (vk0,vk0+1), 4 heads ----
    const int u = tid & 255;
    const int vk0 = (u & 63) * 2;
    const int hq = u >> 6;                   // head quad 0..3
    const int vpart = hq >> 1, jb = (hq & 1) * 4;
    const _Float16* vsrcA = Vg + (size_t)vk0 * 1024 + vpart * 8 + jb;
    const int vbw3 = ((((vk0 >> 4) * 256) + ((vk0 >> 3) & 1) * 128 + vpart * 64 + (vk0 & 7))
                      ^ (((vk0 >> 3) & 7) << 3)) ^ (jb * 8);

    // ---- compute-side V read: single base reg + folded per-pvblk immediates ----
    // addr(s) = ((vb0 ^ ((s&3)<<4)) | ((s&3)<<8) | ((s>>2)<<10)) & vmask
    const int vb0 = h5 * 128 + ((n & 8) | ((n & 7) ^ h5)) * 8;
    const int vmask = (n < 16) ? -1 : 0;     // ones-lanes: offset 0 -> broadcast
    const _Float16* vrb = (n < 16) ? VA : ones;
    const int vbufstep = (n < 16) ? 2048 : 0;

    // ---- prologue: stage chunk 0 into buf 0 ----
    if (tid < 256) {
        GLOAD_LDS16(ksrc, kdst);
    } else {
        f16x4 va = *(const f16x4*)(vsrcA);
        f16x4 vb = *(const f16x4*)(vsrcA + 1024);
#pragma unroll
        for (int jj = 0; jj < 4; jj++) {
            f16x2 pr; pr[0] = va[jj]; pr[1] = vb[jj];
            *(f16x2*)(VA + (vbw3 ^ (jj * 8))) = pr;
        }
    }

    for (int c = 0; c < 8; c++) {            // 128-key chunks
        __syncthreads();                     // buf[c&1] staged; buf[c&1^1] free
        const int cb = c & 1;
        f16x4 va, vb;
        if (c < 7) {                         // issue next chunk's staging early
            if (tid < 256) {
                GLOAD_LDS16(ksrc + (size_t)((c + 1) * 128) * 1024, kdst + (cb ^ 1) * 2048);
            } else {
                va = *(const f16x4*)(vsrcA + (size_t)((c + 1) * 128) * 1024);
                vb = *(const f16x4*)(vsrcA + (size_t)((c + 1) * 128) * 1024 + 1024);
            }
        }
        const _Float16* akc = KA + cb * 2048;
        const _Float16* vrbc = vrb + cb * vbufstep;

        __builtin_amdgcn_s_setprio(1);
#pragma unroll
        for (int t = 0; t < 4; t++) {        // 32 keys per iteration
            f16x8 ak = *(const f16x8*)(akc + (t * 64 + lane) * 8);
            f32x16 s = __builtin_amdgcn_mfma_f32_32x32x16_f16(ak, qf, zero16, 0, 0, 0);
            float p[16];
#pragma unroll
            for (int i = 0; i < 16; i++) p[i] = __builtin_amdgcn_exp2f(s[i]);
            f16x8 pb0 = pack8f(p);           // keys t*32 + 0..15  (k=h5*8+j)
            f16x8 pb1 = pack8f(p + 8);       // keys t*32 + 16..31
            const int o0 = ((vb0 ^ (((2 * t) & 3) << 4)) | (((2 * t) & 3) << 8)
                            | (((2 * t) >> 2) << 10)) & vmask;
            const int o1 = ((vb0 ^ (((2 * t + 1) & 3) << 4)) | (((2 * t + 1) & 3) << 8)
                            | (((2 * t + 1) >> 2) << 10)) & vmask;
            f16x8 av0 = *(const f16x8*)(vrbc + o0);
            f16x8 av1 = *(const f16x8*)(vrbc + o1);
            acc = __builtin_amdgcn_mfma_f32_32x32x16_f16(av0, pb0, acc, 0, 0, 0);
            acc = __builtin_amdgcn_mfma_f32_32x32x16_f16(av1, pb1, acc, 0, 0, 0);
        }
        __builtin_amdgcn_s_setprio(0);

        if (c < 7 && tid >= 256) {           // write-late: V regs -> buf^1
#pragma unroll
            for (int jj = 0; jj < 4; jj++) {
                f16x2 pr; pr[0] = va[jj]; pr[1] = vb[jj];
                *(f16x2*)(VA + (cb ^ 1) * 2048 + (vbw3 ^ (jj * 8))) = pr;
            }
        }
    }

    // acc C-layout: col q=n; regs 0-7 -> heads, regs 8-15 -> L (all equal = key-sum).
    float rl = 1.0f / acc[8];
    f16x4 o0, o1;
#pragma unroll
    for (int i = 0; i < 4; i++) o0[i] = (_Float16)(acc[i] * rl);       // heads 4*h5+0..3
#pragma unroll
    for (int i = 0; i < 4; i++) o1[i] = (_Float16)(acc[4 + i] * rl);   // heads 4*h5+8..11
    _Float16* ob = Ah + (size_t)(b * 1024 + q0 + n) * 1024 + g * 16 + h5 * 4;
    *(f16x4*)(ob) = o0;
    *(f16x4*)(ob + 8) = o1;
}

extern "C" void kernel_launch(void* const* d_in, const int* in_sizes, int n_in,
                              void* d_out, int out_size, void* d_ws, size_t ws_size,
                              hipStream_t stream) {
    const float* x1 = (const float*)d_in[0];
    const float* x2 = (const float*)d_in[1];
    const float* Wq = (const float*)d_in[2];
    const float* Wk = (const float*)d_in[3];
    const float* Wv = (const float*)d_in[4];
    const float* Wo = (const float*)d_in[5];

    char* ws = (char*)d_ws;
    const size_t MB = 1u << 20;
    if (ws_size < 56 * MB) return;

    _Float16* x1h = (_Float16*)(ws + 0 * MB);   // 4096x1024
    _Float16* x2h = (_Float16*)(ws + 8 * MB);   // 4096x1024
    _Float16* WqT = (_Float16*)(ws + 16 * MB);  // 1024x1024 (N,K)
    _Float16* WkT = (_Float16*)(ws + 18 * MB);  // contiguous with WvT -> stacked (2048,1024)
    _Float16* WvT = (_Float16*)(ws + 20 * MB);
    _Float16* WoT = (_Float16*)(ws + 22 * MB);
    _Float16* Qh  = (_Float16*)(ws + 24 * MB);  // 4096x1024
    _Float16* Kh  = (_Float16*)(ws + 32 * MB);
    _Float16* Vh  = (_Float16*)(ws + 40 * MB);
    _Float16* Ah  = (_Float16*)(ws + 48 * MB);

    prep_kernel<<<12288, 256, 0, stream>>>(x1, x2, Wq, Wk, Wv, Wo,
                                           x1h, x2h, WqT, WkT, WvT, WoT);

    gemm_qkv_kernel<<<768, 256, 0, stream>>>(x1h, x2h, WqT, WkT, Qh, Kh, Vh);

    attn_kernel<<<1024, 512, 0, stream>>>(Qh, Kh, Vh, Ah);

    gemm_wo_kernel<<<512, 256, 0, stream>>>(Ah, WoT, (float*)d_out);
}